// Round 3
// baseline (718.681 us; speedup 1.0000x reference)
//
#include <hip/hip_runtime.h>

#define N_NODES 100000
#define F_IN 128
#define HD 16
#define NB ((N_NODES + 255) / 256)   // 391 blocks of 256 nodes

// ---------------- CSR build: histogram -> scan -> scatter ----------------

__global__ void k_zero(int* __restrict__ c, int n) {
    int i = blockIdx.x * blockDim.x + threadIdx.x;
    if (i < n) c[i] = 0;
}

__global__ void k_hist(const int* __restrict__ dst, int* __restrict__ cnt, int E) {
    int i = blockIdx.x * blockDim.x + threadIdx.x;
    int e0 = i * 4;
    if (e0 + 3 < E) {
        int4 d = *(const int4*)(dst + e0);
        atomicAdd(&cnt[d.x], 1); atomicAdd(&cnt[d.y], 1);
        atomicAdd(&cnt[d.z], 1); atomicAdd(&cnt[d.w], 1);
    } else {
        for (int e = e0; e < E; ++e) atomicAdd(&cnt[dst[e]], 1);
    }
}

__global__ void k_dinv(const int* __restrict__ cnt, float* __restrict__ dinv, int n) {
    int i = blockIdx.x * blockDim.x + threadIdx.x;
    if (i < n) dinv[i] = rsqrtf((float)(cnt[i] + 1));  // +1 = self-loop, so deg >= 1
}

__global__ __launch_bounds__(256) void k_bsum(const int* __restrict__ cnt, int* __restrict__ part) {
    __shared__ int s[256];
    int i = blockIdx.x * 256 + threadIdx.x;
    s[threadIdx.x] = (i < N_NODES) ? cnt[i] : 0;
    __syncthreads();
    for (int off = 128; off > 0; off >>= 1) {
        if (threadIdx.x < off) s[threadIdx.x] += s[threadIdx.x + off];
        __syncthreads();
    }
    if (threadIdx.x == 0) part[blockIdx.x] = s[0];
}

// single-block exclusive scan of NB partials (NB=391 < 512)
__global__ __launch_bounds__(512) void k_pscan(int* __restrict__ part) {
    __shared__ int s[512];
    int t = threadIdx.x;
    int v = (t < NB) ? part[t] : 0;
    s[t] = v; __syncthreads();
    for (int off = 1; off < 512; off <<= 1) {
        int x = (t >= off) ? s[t - off] : 0;
        __syncthreads();
        s[t] += x;
        __syncthreads();
    }
    if (t < NB) part[t] = s[t] - v;  // exclusive
}

__global__ __launch_bounds__(256) void k_lscan(const int* __restrict__ cnt, const int* __restrict__ part,
                                               int* __restrict__ rs, int* __restrict__ cur) {
    __shared__ int s[256];
    int t = threadIdx.x;
    int i = blockIdx.x * 256 + t;
    int v = (i < N_NODES) ? cnt[i] : 0;
    s[t] = v; __syncthreads();
    for (int off = 1; off < 256; off <<= 1) {
        int x = (t >= off) ? s[t - off] : 0;
        __syncthreads();
        s[t] += x;
        __syncthreads();
    }
    if (i < N_NODES) {
        int r = part[blockIdx.x] + s[t] - v;  // exclusive row start
        rs[i] = r;
        cur[i] = r;  // mutable cursor copy for the scatter
    }
}

__global__ void k_scatter(const int* __restrict__ src, const int* __restrict__ dst,
                          int* __restrict__ cur, int* __restrict__ srt, int E) {
    int e = blockIdx.x * blockDim.x + threadIdx.x;
    if (e < E) {
        int p = atomicAdd(&cur[dst[e]], 1);   // 4B int atomic, L2-resident counters
        srt[p] = src[e];
    }
}

// ---------------- dense: h = act(in) @ W ----------------
// 16 nodes per 256-thread block; W (128x16) + x-tile staged in LDS.

__global__ __launch_bounds__(256) void k_h1(
        const float* __restrict__ x, const float* __restrict__ W1,
        float* __restrict__ h1) {
    __shared__ float ws[F_IN * HD];
    __shared__ float xs[16][F_IN + 1];
    const int t = threadIdx.x;
    const int node0 = blockIdx.x * 16;

    for (int i = t; i < F_IN * HD; i += 256) ws[i] = W1[i];
    for (int i = t; i < 16 * F_IN; i += 256) {
        int r = i >> 7, c = i & 127;
        int n = node0 + r;
        xs[r][c] = (n < N_NODES) ? x[n * F_IN + c] : 0.0f;
    }
    __syncthreads();

    const int row = t >> 4, col = t & 15;
    const int node = node0 + row;
    float acc = 0.0f;
#pragma unroll 8
    for (int k = 0; k < F_IN; ++k)
        acc += xs[row][k] * ws[k * HD + col];

    if (node < N_NODES) h1[node * HD + col] = acc;
}

__global__ __launch_bounds__(256) void k_h2(
        const float* __restrict__ out1, const float* __restrict__ W2,
        float* __restrict__ h2) {
    __shared__ float ws[HD * HD];
    __shared__ float as[16][HD + 1];
    const int t = threadIdx.x;
    const int node0 = blockIdx.x * 16;

    if (t < HD * HD) ws[t] = W2[t];
    {
        int n = node0 + (t >> 4);
        float v = (n < N_NODES) ? out1[node0 * HD + t] : 0.0f;
        as[t >> 4][t & 15] = fmaxf(v, 0.0f);   // relu fused on load
    }
    __syncthreads();

    const int row = t >> 4, col = t & 15;
    const int node = node0 + row;
    float acc = 0.0f;
#pragma unroll
    for (int k = 0; k < HD; ++k)
        acc += as[row][k] * ws[k * HD + col];

    if (node < N_NODES) h2[node * HD + col] = acc;
}

// ---------------- atomic-free aggregation: one wave per node ----------------
// out[d][c] = dinv[d] * ( sum_{e in CSR[d]} dinv[src]*h[src][c] + dinv[d]*h[d][c] ) + b[c]
// 4 edges in parallel (lane>>4) x 16 features (lane&15); butterfly reduce across quarters.

__global__ __launch_bounds__(256) void k_agg(
        const int* __restrict__ srt, const int* __restrict__ rs, const int* __restrict__ cnt,
        const float* __restrict__ dinv, const float* __restrict__ h,
        const float* __restrict__ b, float* __restrict__ out) {
    const int node = blockIdx.x * 4 + (threadIdx.x >> 6);
    if (node >= N_NODES) return;   // uniform per wave
    const int lane = threadIdx.x & 63;
    const int c = lane & 15;
    const int q = lane >> 4;

    const int beg = rs[node];
    const int n   = cnt[node];

    float acc = 0.0f;
    for (int i = q; i < n; i += 4) {
        int s = srt[beg + i];                 // broadcast within 16-lane quarter
        acc += dinv[s] * h[s * HD + c];       // 64B coalesced gather per quarter
    }
    acc += __shfl_xor(acc, 16);
    acc += __shfl_xor(acc, 32);

    if (q == 0) {
        float dd = dinv[node];
        float self = dd * h[node * HD + c];
        out[node * HD + c] = dd * (acc + self) + b[c];
    }
}

// ---------------- launch ----------------

extern "C" void kernel_launch(void* const* d_in, const int* in_sizes, int n_in,
                              void* d_out, int out_size, void* d_ws, size_t ws_size,
                              hipStream_t stream) {
    const float* x   = (const float*)d_in[0];
    const int*   ei  = (const int*)d_in[1];
    const float* W1  = (const float*)d_in[2];
    const float* b1  = (const float*)d_in[3];
    const float* W2  = (const float*)d_in[4];
    const float* b2  = (const float*)d_in[5];
    float* out = (float*)d_out;

    const int E = in_sizes[1] / 2;
    const int* src = ei;
    const int* dst = ei + E;

    // workspace layout (bytes)
    char* wsb = (char*)d_ws;
    int*   cnt  = (int*)(wsb + 0x000000);    // 400 KB
    int*   rs   = (int*)(wsb + 0x080000);    // row starts
    int*   cur  = (int*)(wsb + 0x100000);    // scatter cursors
    float* dinv = (float*)(wsb + 0x180000);
    int*   part = (int*)(wsb + 0x200000);    // scan partials (NB=391)
    float* bufA = (float*)(wsb + 0x280000);  // h1, later h2 (6.4 MB)
    float* bufB = (float*)(wsb + 0x900000);  // out1 (6.4 MB)
    int*   srt  = (int*)(wsb + 0x1000000);   // sorted src (12.8 MB)

    const int histBlocks = (E / 4 + 255) / 256;
    const int edgeBlocks = (E + 255) / 256;
    const int tileBlocks = (N_NODES + 15) / 16;
    const int aggBlocks  = (N_NODES + 3) / 4;

    // CSR build (once, reused by both layers)
    k_zero<<<NB, 256, 0, stream>>>(cnt, N_NODES);
    k_hist<<<histBlocks, 256, 0, stream>>>(dst, cnt, E);
    k_dinv<<<NB, 256, 0, stream>>>(cnt, dinv, N_NODES);
    k_bsum<<<NB, 256, 0, stream>>>(cnt, part);
    k_pscan<<<1, 512, 0, stream>>>(part);
    k_lscan<<<NB, 256, 0, stream>>>(cnt, part, rs, cur);
    k_scatter<<<edgeBlocks, 256, 0, stream>>>(src, dst, cur, srt, E);

    // layer 1
    k_h1<<<tileBlocks, 256, 0, stream>>>(x, W1, bufA);
    k_agg<<<aggBlocks, 256, 0, stream>>>(srt, rs, cnt, dinv, bufA, b1, bufB);

    // layer 2
    k_h2<<<tileBlocks, 256, 0, stream>>>(bufB, W2, bufA);
    k_agg<<<aggBlocks, 256, 0, stream>>>(srt, rs, cnt, dinv, bufA, b2, out);
}